// Round 7
// baseline (226.663 us; speedup 1.0000x reference)
//
#include <hip/hip_runtime.h>
#include <hip/hip_bf16.h>
#include <cstdint>
#include <cstddef>

typedef __bf16 bf16_t;
typedef __bf16 bf16x8 __attribute__((ext_vector_type(8)));
typedef __bf16 bf16x4 __attribute__((ext_vector_type(4)));
typedef float f32x4 __attribute__((ext_vector_type(4)));

#define MFMA16(a, b, c) __builtin_amdgcn_mfma_f32_16x16x32_bf16((a), (b), (c), 0, 0, 0)

__device__ __forceinline__ bf16x8 ld8f(const float* p) {
    f32x4 a = *reinterpret_cast<const f32x4*>(p);
    f32x4 b = *reinterpret_cast<const f32x4*>(p + 4);
    bf16x8 r;
    r[0] = (bf16_t)a[0]; r[1] = (bf16_t)a[1]; r[2] = (bf16_t)a[2]; r[3] = (bf16_t)a[3];
    r[4] = (bf16_t)b[0]; r[5] = (bf16_t)b[1]; r[6] = (bf16_t)b[2]; r[7] = (bf16_t)b[3];
    return r;
}
__device__ __forceinline__ bf16x8 ldg8(const bf16_t* p) {
    return *reinterpret_cast<const bf16x8*>(p);
}
// async global->LDS DMA, 16B/lane; lds dest = uniform base + lane*16B
__device__ __forceinline__ void gload_lds16(const bf16_t* g, bf16_t* l) {
    __builtin_amdgcn_global_load_lds((const __attribute__((address_space(1))) void*)g,
                                     (__attribute__((address_space(3))) void*)l, 16, 0, 0);
}

// ---------------------------------------------------------------------------
// K0 k_prep (combined, 3-dispatch config):
//   big grid (8448): blocks 0..8191 = pack H,Z f32 -> A bf16[16384][1024],
//                    blocks 8192..8447 = fused-weight GEMM (LAUNCHED LAST so
//                    they run while/after the pack drains -> uncongested
//                    weight-load latency; R2/R3 showed contention, not the
//                    pack, limits this kernel).
//   small grid (256, fallback): all blocks = weight GEMM (gridDim-gated).
// Weight GEMM keeps the proven depth-2 register prefetch; bits of W and A
// are identical to prior rounds.
// ---------------------------------------------------------------------------
__global__ __launch_bounds__(256) void k_prep(
    const float* __restrict__ H, const float* __restrict__ Z,
    const float* __restrict__ Whk, const float* __restrict__ Whv,
    const float* __restrict__ Wzk, const float* __restrict__ Wzv,
    const float* __restrict__ Wq,  const float* __restrict__ Wout,
    bf16_t* __restrict__ W, bf16_t* __restrict__ A)
{
    const int tid = threadIdx.x;
    const int nblk = (int)gridDim.x;
    if (nblk > 256 && (int)blockIdx.x < nblk - 256) {
        const int row = blockIdx.x * 2 + (tid >> 7);
        const int c8 = (tid & 127) * 8;
        const float* src = (c8 < 512) ? (H + (size_t)row * 512 + c8)
                                      : (Z + (size_t)row * 512 + (c8 - 512));
        *reinterpret_cast<bf16x8*>(A + (size_t)row * 1024 + c8) = ld8f(src);
        return;
    }
    const int wb = (nblk > 256) ? ((int)blockIdx.x - (nblk - 256)) : (int)blockIdx.x;
    __shared__ bf16_t LA[64][40];
    __shared__ bf16_t LB[64][40];
    const int lane = tid & 63, wid = tid >> 6;
    const int L15 = lane & 15, qd = lane >> 4;
    const int quad = wb & 3, tile = wb >> 2;
    const int ti = (tile >> 3) * 64, tj = (tile & 7) * 64;
    const float RS = 0.04419417382415922f;  // 1/sqrt(512)

    const float* Lp; const float* Rp; int orow, ocol; float scale; int transL;
    switch (quad) {
        case 0:  Lp = Wq;           Rp = Whk; orow = 0;   ocol = 0;   scale = RS;  transL = 1; break;
        case 1:  Lp = Wout;         Rp = Whv; orow = 512; ocol = 0;   scale = 1.f; transL = 0; break;
        case 2:  Lp = Wq + 524288;  Rp = Wzk; orow = 0;   ocol = 512; scale = RS;  transL = 1; break;
        default: Lp = Wout + 1024;  Rp = Wzv; orow = 512; ocol = 512; scale = 1.f; transL = 0; break;
    }

    const int li  = tid & 63;
    const int lk8 = (tid >> 6) * 8;
    const int di  = tid >> 2;
    const int dk0 = (tid & 3) * 8;

    float fa0[8], fb0[8], fa1[8], fb1[8];
    auto loadT = [&](int kc, float* fa, float* fb) {
        const int k0 = kc * 32;
        if (transL) {
#pragma unroll
            for (int j = 0; j < 8; j++)
                fa[j] = Lp[(size_t)(k0 + lk8 + j) * 512 + ti + li];
        } else {
            const float* p = Lp + (size_t)(ti + di) * 2048 + k0 + dk0;
            f32x4 v0 = *reinterpret_cast<const f32x4*>(p);
            f32x4 v1 = *reinterpret_cast<const f32x4*>(p + 4);
#pragma unroll
            for (int j = 0; j < 4; j++) { fa[j] = v0[j]; fa[4 + j] = v1[j]; }
        }
#pragma unroll
        for (int j = 0; j < 8; j++)
            fb[j] = Rp[(size_t)(k0 + lk8 + j) * 512 + tj + li];
    };

    f32x4 acc[4];
#pragma unroll
    for (int t = 0; t < 4; t++) acc[t] = (f32x4){0.f, 0.f, 0.f, 0.f};

    loadT(0, fa0, fb0);
    loadT(1, fa1, fb1);

#define WSTEP(FA, FB, KPRE) { \
        __syncthreads(); \
        bf16x8 pa, pb; \
        _Pragma("unroll") \
        for (int j = 0; j < 8; j++) { pa[j] = (bf16_t)FA[j]; pb[j] = (bf16_t)FB[j]; } \
        if (transL) *reinterpret_cast<bf16x8*>(&LA[li][lk8]) = pa; \
        else        *reinterpret_cast<bf16x8*>(&LA[di][dk0]) = pa; \
        *reinterpret_cast<bf16x8*>(&LB[li][lk8]) = pb; \
        __syncthreads(); \
        if ((KPRE) < 32) loadT((KPRE), FA, FB); \
        bf16x8 afr = *reinterpret_cast<bf16x8*>(&LA[wid * 16 + L15][qd * 8]); \
        _Pragma("unroll") \
        for (int t = 0; t < 4; t++) { \
            bf16x8 bfr = *reinterpret_cast<bf16x8*>(&LB[t * 16 + L15][qd * 8]); \
            acc[t] = MFMA16(afr, bfr, acc[t]); \
        } }

#pragma unroll 1
    for (int kc = 0; kc < 32; kc += 2) {
        WSTEP(fa0, fb0, kc + 2);
        WSTEP(fa1, fb1, kc + 3);
    }
#undef WSTEP

#pragma unroll
    for (int t = 0; t < 4; t++) {
        int col = ocol + tj + t * 16 + L15;
#pragma unroll
        for (int r = 0; r < 4; r++) {
            int row = orow + ti + wid * 16 + qd * 4 + r;
            W[(size_t)row * 1024 + col] = (bf16_t)(acc[t][r] * scale);
        }
    }
}

// ---------------------------------------------------------------------------
// K2 k_gemm: measured-best vmcnt(6) schedule + NEW cross-tile read-ahead:
// next tile's A0/B0 fragment reads (the 12-read P0 burst) moved to the
// current tile's P3, AFTER the boundary vmcnt (at which point the whole
// next tile is provably in LDS). Phase read histogram 12/4/8/0 -> 0/4/8/12;
// P0's lgkmcnt(0) now waits on reads issued two barriers earlier (~free).
// Region-hazard walk: each pre-read is lgkm-waited at next P0, >=1 barrier
// before any DMA write to its region (U3->B^1 writes hit that region only
// two tiles later). MFMA order unchanged -> bit-identical output.
// ---------------------------------------------------------------------------
__global__ __launch_bounds__(512, 2) void k_gemm(
    const bf16_t* __restrict__ A, const bf16_t* __restrict__ W,
    bf16_t* __restrict__ G, bf16_t* __restrict__ VT)
{
    __shared__ bf16_t LA[2][256 * 64];
    __shared__ bf16_t LB[2][256 * 64];
    const int tid = threadIdx.x, lane = tid & 63, wid = tid >> 6;
    const int L15 = lane & 15, qd = lane >> 4;
    // XCD = bid&7 (round-robin dispatch); blocks sharing mb land on same XCD.
    const int mb = (blockIdx.x & 7) + (((blockIdx.x >> 3) & 7) << 3);
    const int nb = blockIdx.x >> 6;
    const int m0 = mb * 256, n0 = nb * 256;
    const int wm = wid >> 2, wn = wid & 3;

    // ---- staging addressing ----
    const int si = tid >> 3;                           // 0..63
    const int gs = ((tid & 7) ^ (si & 7)) * 8;         // swizzled src chunk
    const int rowB = (si & 31) + ((si >> 5) << 6);     // B stripe row base
    const bf16_t* Ag = A + (size_t)(m0 + si) * 1024 + gs;
    const bf16_t* Wg = W + (size_t)(n0 + rowB) * 1024 + gs;
    const int loA = tid * 8;                                             // elems
    const int loB = ((si & 31) << 6) + ((si >> 5) << 12) + ((tid & 7) << 3);

    // ---- fragment read offsets (swizzled) ----
    const int r7 = L15 & 7;
    const int ea0 = (qd ^ r7) * 8;
    const int ea1 = ((4 + qd) ^ r7) * 8;
    const int arow = (wm * 128 + L15) * 64;            // + mh*4096 + mt*1024
    const int brow = (wn * 64 + L15) * 64;             // + nh*2048 + nt*1024

    f32x4 acc[8][4];
#pragma unroll
    for (int mt = 0; mt < 8; mt++)
#pragma unroll
        for (int nt = 0; nt < 4; nt++) acc[mt][nt] = (f32x4){0.f, 0.f, 0.f, 0.f};

    bf16x8 af[4][2];        // current mh's A frags
    bf16x8 bfr[2][2][2];    // all B frags [nh][nt][ks]

#define STG_U0(B, ktn) { gload_lds16(Ag + (size_t)(ktn) * 64,          &LA[B][loA]); \
                         gload_lds16(Ag + (size_t)(ktn) * 64 + 131072, &LA[B][8192 + loA]); }
#define STG_U2(B, ktn) { gload_lds16(Ag + (size_t)(ktn) * 64 + 65536,  &LA[B][4096 + loA]); \
                         gload_lds16(Ag + (size_t)(ktn) * 64 + 196608, &LA[B][12288 + loA]); }
#define STG_U3(B, ktn) { gload_lds16(Wg + (size_t)(ktn) * 64,          &LB[B][loB]); \
                         gload_lds16(Wg + (size_t)(ktn) * 64 + 131072, &LB[B][8192 + loB]); }
#define STG_U1(B, ktn) { gload_lds16(Wg + (size_t)(ktn) * 64 + 32768,  &LB[B][2048 + loB]); \
                         gload_lds16(Wg + (size_t)(ktn) * 64 + 163840, &LB[B][10240 + loB]); }
#define LDA(B, mh) { _Pragma("unroll") for (int mt = 0; mt < 4; mt++) { \
        const bf16_t* p_ = &LA[B][arow + (mh) * 4096 + mt * 1024]; \
        af[mt][0] = *reinterpret_cast<const bf16x8*>(p_ + ea0); \
        af[mt][1] = *reinterpret_cast<const bf16x8*>(p_ + ea1); } }
#define LDB(B, nh) { _Pragma("unroll") for (int nt = 0; nt < 2; nt++) { \
        const bf16_t* p_ = &LB[B][brow + (nh) * 2048 + nt * 1024]; \
        bfr[nh][nt][0] = *reinterpret_cast<const bf16x8*>(p_ + ea0); \
        bfr[nh][nt][1] = *reinterpret_cast<const bf16x8*>(p_ + ea1); } }
#define MMAQ(mh, nh) { _Pragma("unroll") for (int mt = 0; mt < 4; mt++) \
        _Pragma("unroll") for (int nt = 0; nt < 2; nt++) { \
            acc[(mh)*4+mt][(nh)*2+nt] = MFMA16(af[mt][0], bfr[nh][nt][0], acc[(mh)*4+mt][(nh)*2+nt]); \
            acc[(mh)*4+mt][(nh)*2+nt] = MFMA16(af[mt][1], bfr[nh][nt][1], acc[(mh)*4+mt][(nh)*2+nt]); } }
#define BARX() __builtin_amdgcn_s_barrier()
#define PR1() __builtin_amdgcn_s_setprio(1)
#define PR0() __builtin_amdgcn_s_setprio(0)
#define WAIT_LGKM() { asm volatile("s_waitcnt lgkmcnt(0)" ::: "memory"); \
                      __builtin_amdgcn_sched_barrier(0); }
#define VMC6() { asm volatile("s_waitcnt vmcnt(6)" ::: "memory"); \
                 __builtin_amdgcn_sched_barrier(0); }
#define VMC0() { asm volatile("s_waitcnt vmcnt(0)" ::: "memory"); \
                 __builtin_amdgcn_sched_barrier(0); }
#define VMNONE() {}

    // TILE(B = buffer of tile t, S3 = stage U3(kt1), SN = stage U0/U1/U2(kt2),
    //      RA = read-ahead next tile's A0/B0 after the boundary wait)
#define TILE(B, S3, SN, kt1, kt2, VMW, RA) { \
        /* P0: frags A0,B0 pre-read at previous P3 */ \
        if (S3) STG_U3((B) ^ 1, kt1); \
        BARX(); WAIT_LGKM(); PR1(); MMAQ(0, 0); PR0(); BARX(); \
        /* P1 */ LDB(B, 1); \
        if (SN) STG_U0(B, kt2); \
        BARX(); WAIT_LGKM(); PR1(); MMAQ(0, 1); PR0(); BARX(); \
        /* P2 */ LDA(B, 1); \
        if (SN) STG_U1(B, kt2); \
        BARX(); WAIT_LGKM(); PR1(); MMAQ(1, 0); PR0(); BARX(); \
        /* P3 */ \
        if (SN) STG_U2(B, kt2); \
        BARX(); PR1(); MMAQ(1, 1); PR0(); \
        VMW; \
        if (RA) { LDA((B) ^ 1, 0); LDB((B) ^ 1, 0); } \
        BARX(); }

    // prologue: tile0 complete + tile1 U0,U1,U2; vmcnt(6) completes tile 0;
    // then pre-read tile 0's A0/B0 (waited at tile 0 P0).
    STG_U0(0, 0); STG_U1(0, 0); STG_U2(0, 0); STG_U3(0, 0);
    STG_U0(1, 1); STG_U1(1, 1); STG_U2(1, 1);
    VMC6(); BARX();
    LDA(0, 0); LDB(0, 0);

    for (int t = 0; t < 14; t += 2) {
        TILE(0, 1, 1, t + 1, t + 2, VMC6(), 1);
        TILE(1, 1, 1, t + 2, t + 3, VMC6(), 1);
    }
    TILE(0, 1, 0, 15, 0, VMC0(), 1);   // tile 14: stage U3(15), drain, pre-read 15
    TILE(1, 0, 0, 0, 0, VMNONE(), 0);  // tile 15: no staging, no wait

#undef TILE
#undef STG_U0
#undef STG_U1
#undef STG_U2
#undef STG_U3
#undef LDA
#undef LDB
#undef MMAQ

    if (nb < 2) {
#pragma unroll
        for (int mt = 0; mt < 8; mt++) {
            int mrow = m0 + wm * 128 + mt * 16 + qd * 4;
#pragma unroll
            for (int nt = 0; nt < 4; nt++) {
                int j = n0 + wn * 64 + nt * 16 + L15;
#pragma unroll
                for (int r = 0; r < 4; r++)
                    G[(size_t)(mrow + r) * 512 + j] = (bf16_t)acc[mt][nt][r];
            }
        }
    } else {
#pragma unroll
        for (int mt = 0; mt < 8; mt++) {
            int mrow = m0 + wm * 128 + mt * 16 + qd * 4;
            int n = mrow >> 6, kl = mrow & 63;
#pragma unroll
            for (int nt = 0; nt < 4; nt++) {
                int dloc = (n0 - 512) + wn * 64 + nt * 16 + L15;
                bf16x4 pk;
#pragma unroll
                for (int r = 0; r < 4; r++) pk[r] = (bf16_t)acc[mt][nt][r];
                *reinterpret_cast<bf16x4*>(&VT[(size_t)n * 32768 + (size_t)dloc * 64 + kl]) = pk;
            }
        }
    }
}

// ---------------------------------------------------------------------------
// K3 k_attn: unchanged (1024-block version from the best-measured run).
// ---------------------------------------------------------------------------
__global__ __launch_bounds__(256) void k_attn(
    const bf16_t* __restrict__ A,
    const bf16_t* __restrict__ G, const bf16_t* __restrict__ VT,
    const float* __restrict__ lng, const float* __restrict__ lnb,
    float* __restrict__ out)
{
    __shared__ float  Sl[16][68];
    __shared__ bf16_t Sp[16][72];
    __shared__ float  Rs[4][16];
    __shared__ float  Rq[4][16];
    const int n = blockIdx.x & 255, ks4 = blockIdx.x >> 8;
    const int tid = threadIdx.x, lane = tid & 63, w = tid >> 6;
    const int L15 = lane & 15, qd = lane >> 4;
    const bf16_t* Gb = G + (size_t)n * 32768 + (size_t)(ks4 * 16) * 512;
    const bf16_t* Vb = VT + (size_t)n * 32768;
    const bf16_t* Ab = A + (size_t)n * 64 * 1024;

    bf16x8 bv[2][8];
#pragma unroll
    for (int kq = 0; kq < 2; kq++)
#pragma unroll
        for (int dt = 0; dt < 8; dt++)
            bv[kq][dt] = ldg8(Vb + (size_t)(w * 128 + dt * 16 + L15) * 64 + kq * 32 + qd * 8);

    {   // logits[16 k-rows][q-tile w], two independent MFMA chains
        f32x4 lg0 = (f32x4){0.f, 0.f, 0.f, 0.f};
        f32x4 lg1 = (f32x4){0.f, 0.f, 0.f, 0.f};
        const bf16_t* ga = Gb + (size_t)L15 * 512 + qd * 8;
        const bf16_t* ab = Ab + (size_t)(w * 16 + L15) * 1024 + qd * 8;
#pragma unroll
        for (int ks = 0; ks < 16; ks += 2) {
            lg0 = MFMA16(ldg8(ga + ks * 32),      ldg8(ab + ks * 32),      lg0);
            lg1 = MFMA16(ldg8(ga + ks * 32 + 32), ldg8(ab + ks * 32 + 32), lg1);
        }
        f32x4 lg = lg0 + lg1;
#pragma unroll
        for (int r = 0; r < 4; r++)
            Sl[qd * 4 + r][w * 16 + L15] = lg[r];
    }
    __syncthreads();
    {   // softmax over q (64): 16 threads/row, 4 cols each
        int row = tid >> 4, c0 = (tid & 15) * 4;
        float4 v = *reinterpret_cast<float4*>(&Sl[row][c0]);
        float mx = fmaxf(fmaxf(v.x, v.y), fmaxf(v.z, v.w));
#pragma unroll
        for (int m = 1; m < 16; m <<= 1) mx = fmaxf(mx, __shfl_xor(mx, m));
        float e0 = __expf(v.x - mx), e1 = __expf(v.y - mx);
        float e2 = __expf(v.z - mx), e3 = __expf(v.w - mx);
        float s = e0 + e1 + e2 + e3;
#pragma unroll
        for (int m = 1; m < 16; m <<= 1) s += __shfl_xor(s, m);
        float inv = 1.0f / s;
        bf16x4 p;
        p[0] = (bf16_t)(e0 * inv); p[1] = (bf16_t)(e1 * inv);
        p[2] = (bf16_t)(e2 * inv); p[3] = (bf16_t)(e3 * inv);
        *reinterpret_cast<bf16x4*>(&Sp[row][c0]) = p;
    }
    __syncthreads();

    f32x4 acc[8];
#pragma unroll
    for (int dt = 0; dt < 8; dt++) acc[dt] = (f32x4){0.f, 0.f, 0.f, 0.f};
#pragma unroll
    for (int kq = 0; kq < 2; kq++) {
        bf16x8 ap = *reinterpret_cast<bf16x8*>(&Sp[L15][kq * 32 + qd * 8]);
#pragma unroll
        for (int dt = 0; dt < 8; dt++)
            acc[dt] = MFMA16(ap, bv[kq][dt], acc[dt]);
    }
    float s4[4] = {0.f, 0.f, 0.f, 0.f}, ss4[4] = {0.f, 0.f, 0.f, 0.f};
#pragma unroll
    for (int dt = 0; dt < 8; dt++)
#pragma unroll
        for (int r = 0; r < 4; r++) { float x = acc[dt][r]; s4[r] += x; ss4[r] += x * x; }
#pragma unroll
    for (int m = 1; m < 16; m <<= 1)
#pragma unroll
        for (int r = 0; r < 4; r++) {
            s4[r]  += __shfl_xor(s4[r], m);
            ss4[r] += __shfl_xor(ss4[r], m);
        }
    if (L15 == 0)
#pragma unroll
        for (int r = 0; r < 4; r++) {
            int row = qd * 4 + r;
            Rs[w][row] = s4[r];
            Rq[w][row] = ss4[r];
        }
    __syncthreads();
    float mean[4], rstd[4];
#pragma unroll
    for (int r = 0; r < 4; r++) {
        int row = qd * 4 + r;
        float S = Rs[0][row] + Rs[1][row] + Rs[2][row] + Rs[3][row];
        float Q = Rq[0][row] + Rq[1][row] + Rq[2][row] + Rq[3][row];
        float mu = S * (1.f / 512.f);
        float var = Q * (1.f / 512.f) - mu * mu;
        mean[r] = mu;
        rstd[r] = rsqrtf(var + 1e-5f);
    }
    float* ob = out + (size_t)n * 32768 + (size_t)(ks4 * 16) * 512;
#pragma unroll
    for (int dt = 0; dt < 8; dt++) {
        int col = w * 128 + dt * 16 + L15;
        float gg = lng[col], bb = lnb[col];
#pragma unroll
        for (int r = 0; r < 4; r++) {
            int row = qd * 4 + r;
            ob[(size_t)row * 512 + col] = (acc[dt][r] - mean[r]) * rstd[r] * gg + bb;
        }
    }
}

// ---------------------------------------------------------------------------
// Fallback fused per-batch kernel — only if ws too small.
// ---------------------------------------------------------------------------
__global__ __launch_bounds__(1024) void k_batch_fb(
    const float* __restrict__ H, const float* __restrict__ Z,
    const bf16_t* __restrict__ W,
    const float* __restrict__ lng, const float* __restrict__ lnb,
    float* __restrict__ out)
{
    __shared__ __align__(16) char lds_raw[48128];
    bf16_t* lds_bf = (bf16_t*)lds_raw;
    float*  lds_f  = (float*)lds_raw;
    bf16_t* Gbuf = lds_bf;
    float*  Sl   = lds_f;
    bf16_t* VTl  = lds_bf;
    bf16_t* Sp   = lds_bf + 18432;
    float*  Rs   = lds_f + 11520;
    float*  Rq   = lds_f + 11776;

    const int n = blockIdx.x;
    const int tid = threadIdx.x, lane = tid & 63, w = tid >> 6;
    const int L15 = lane & 15, qd = lane >> 4;
    const int strip = w & 3, grp = w >> 2;
    const float* Hb = H + (size_t)n * 32768;
    const float* Zb = Z + (size_t)n * 32768;

    f32x4 a1 = (f32x4){0.f, 0.f, 0.f, 0.f};
    for (int hf = 0; hf < 2; hf++) {
        f32x4 ga[4];
#pragma unroll
        for (int mt = 0; mt < 4; mt++) ga[mt] = (f32x4){0.f, 0.f, 0.f, 0.f};
        const bf16_t* wrow = W + (size_t)(hf * 256 + w * 16 + L15) * 1024;
#pragma unroll 4
        for (int kc = 0; kc < 16; kc++) {
            const int ko = kc * 32 + qd * 8;
            bf16x8 bh = ldg8(wrow + ko);
            bf16x8 bz = ldg8(wrow + 512 + ko);
#pragma unroll
            for (int mt = 0; mt < 4; mt++) {
                bf16x8 ah = ld8f(Hb + (size_t)(mt * 16 + L15) * 512 + ko);
                bf16x8 az = ld8f(Zb + (size_t)(mt * 16 + L15) * 512 + ko);
                ga[mt] = MFMA16(ah, bh, ga[mt]);
                ga[mt] = MFMA16(az, bz, ga[mt]);
            }
        }
        __syncthreads();
#pragma unroll
        for (int mt = 0; mt < 4; mt++)
#pragma unroll
            for (int r = 0; r < 4; r++)
                Gbuf[(size_t)(mt * 16 + qd * 4 + r) * 264 + w * 16 + L15] = (bf16_t)ga[mt][r];
        __syncthreads();
#pragma unroll
        for (int kcf = 0; kcf < 8; kcf++) {
            bf16x8 af = *reinterpret_cast<bf16x8*>(
                &Gbuf[(size_t)(strip * 16 + L15) * 264 + kcf * 32 + qd * 8]);
            bf16x8 bq = ld8f(Hb + (size_t)(grp * 16 + L15) * 512 + hf * 256 + kcf * 32 + qd * 8);
            a1 = MFMA16(af, bq, a1);
        }
    }
    __syncthreads();
#pragma unroll
    for (int r = 0; r < 4; r++)
        Sl[(size_t)(strip * 16 + qd * 4 + r) * 64 + grp * 16 + L15] = a1[r];
    __syncthreads();
    {
        int row = tid >> 4, c0 = (tid & 15) * 4;
        float4 v = *reinterpret_cast<float4*>(&Sl[(size_t)row * 64 + c0]);
        float mx = fmaxf(fmaxf(v.x, v.y), fmaxf(v.z, v.w));
#pragma unroll
        for (int m = 1; m < 16; m <<= 1) mx = fmaxf(mx, __shfl_xor(mx, m));
        float e0 = __expf(v.x - mx), e1 = __expf(v.y - mx);
        float e2 = __expf(v.z - mx), e3 = __expf(v.w - mx);
        float s = e0 + e1 + e2 + e3;
#pragma unroll
        for (int m = 1; m < 16; m <<= 1) s += __shfl_xor(s, m);
        float inv = 1.0f / s;
        bf16x4 p;
        p[0] = (bf16_t)(e0 * inv); p[1] = (bf16_t)(e1 * inv);
        p[2] = (bf16_t)(e2 * inv); p[3] = (bf16_t)(e3 * inv);
        *reinterpret_cast<bf16x4*>(&Sp[(size_t)row * 72 + c0]) = p;
    }
    __syncthreads();

    f32x4 acc[8];
#pragma unroll
    for (int j = 0; j < 8; j++) acc[j] = (f32x4){0.f, 0.f, 0.f, 0.f};
    for (int hf2 = 0; hf2 < 2; hf2++) {
        f32x4 va[4];
#pragma unroll
        for (int mt = 0; mt < 4; mt++) va[mt] = (f32x4){0.f, 0.f, 0.f, 0.f};
        const bf16_t* wrow = W + (size_t)(512 + hf2 * 256 + w * 16 + L15) * 1024;
#pragma unroll 4
        for (int kc = 0; kc < 16; kc++) {
            const int ko = kc * 32 + qd * 8;
            bf16x8 bh = ldg8(wrow + ko);
            bf16x8 bz = ldg8(wrow + 512 + ko);
#pragma unroll
            for (int mt = 0; mt < 4; mt++) {
                bf16x8 ah = ld8f(Hb + (size_t)(mt * 16 + L15) * 512 + ko);
                bf16x8 az = ld8f(Zb + (size_t)(mt * 16 + L15) * 512 + ko);
                va[mt] = MFMA16(ah, bh, va[mt]);
                va[mt] = MFMA16(az, bz, va[mt]);
            }
        }
#pragma unroll
        for (int mt = 0; mt < 4; mt++) {
            bf16x4 pk;
#pragma unroll
            for (int r = 0; r < 4; r++) pk[r] = (bf16_t)va[mt][r];
            *reinterpret_cast<bf16x4*>(&VTl[(size_t)(w * 16 + L15) * 72 + mt * 16 + qd * 4]) = pk;
        }
        __syncthreads();
#pragma unroll
        for (int kcq = 0; kcq < 2; kcq++) {
            bf16x8 ap = *reinterpret_cast<bf16x8*>(
                &Sp[(size_t)(strip * 16 + L15) * 72 + kcq * 32 + qd * 8]);
#pragma unroll
            for (int dt = 0; dt < 4; dt++) {
                bf16x8 bvl = *reinterpret_cast<bf16x8*>(
                    &VTl[(size_t)(grp * 64 + dt * 16 + L15) * 72 + kcq * 32 + qd * 8]);
                acc[hf2 * 4 + dt] = MFMA16(ap, bvl, acc[hf2 * 4 + dt]);
            }
        }
        __syncthreads();
    }
    float s4[4] = {0.f, 0.f, 0.f, 0.f}, ss4[4] = {0.f, 0.f, 0.f, 0.f};
#pragma unroll
    for (int j = 0; j < 8; j++)
#pragma unroll
        for (int r = 0; r < 4; r++) { float x = acc[j][r]; s4[r] += x; ss4[r] += x * x; }
#pragma unroll
    for (int m = 1; m < 16; m <<= 1)
#pragma unroll
        for (int r = 0; r < 4; r++) {
            s4[r]  += __shfl_xor(s4[r], m);
            ss4[r] += __shfl_xor(ss4[r], m);
        }
    if (L15 == 0)
#pragma unroll
        for (int r = 0; r < 4; r++) {
            int row = strip * 16 + qd * 4 + r;
            Rs[grp * 64 + row] = s4[r];
            Rq[grp * 64 + row] = ss4[r];
        }
    __syncthreads();
    float mean[4], rstd[4];
#pragma unroll
    for (int r = 0; r < 4; r++) {
        int row = strip * 16 + qd * 4 + r;
        float S = Rs[row] + Rs[64 + row] + Rs[128 + row] + Rs[192 + row];
        float Q = Rq[row] + Rq[64 + row] + Rq[128 + row] + Rq[192 + row];
        float mu = S * (1.f / 512.f);
        float var = Q * (1.f / 512.f) - mu * mu;
        mean[r] = mu;
        rstd[r] = rsqrtf(var + 1e-5f);
    }
#pragma unroll
    for (int j = 0; j < 8; j++) {
        int col = (j >> 2) * 256 + grp * 64 + (j & 3) * 16 + L15;
        float gg = lng[col], bb = lnb[col];
#pragma unroll
        for (int r = 0; r < 4; r++) {
            int row = strip * 16 + qd * 4 + r;
            out[(size_t)n * 32768 + (size_t)row * 512 + col] =
                (acc[j][r] - mean[r]) * rstd[r] * gg + bb;
        }
    }
}

extern "C" void kernel_launch(void* const* d_in, const int* in_sizes, int n_in,
                              void* d_out, int out_size, void* d_ws, size_t ws_size,
                              hipStream_t stream) {
    const float* H    = (const float*)d_in[0];
    const float* Z    = (const float*)d_in[1];
    const float* Whk  = (const float*)d_in[2];
    const float* Whv  = (const float*)d_in[3];
    const float* Wzk  = (const float*)d_in[4];
    const float* Wzv  = (const float*)d_in[5];
    const float* Wq   = (const float*)d_in[6];
    const float* Wout = (const float*)d_in[7];
    const float* lng  = (const float*)d_in[8];
    const float* lnb  = (const float*)d_in[9];

    bf16_t* W  = (bf16_t*)d_ws;            // [1024][1024]    2 MiB
    bf16_t* A  = W + 1024 * 1024;          // [16384][1024]  32 MiB
    bf16_t* G  = A + (size_t)16384 * 1024; // [16384][512]   16 MiB
    bf16_t* VT = G + (size_t)16384 * 512;  // [256][512][64] 16 MiB
    const size_t need = ((size_t)1024 * 1024 + (size_t)16384 * 1024 +
                         (size_t)16384 * 512 + (size_t)256 * 512 * 64) * 2;

    if (ws_size >= need) {
        k_prep<<<8448, 256, 0, stream>>>(H, Z, Whk, Whv, Wzk, Wzv, Wq, Wout, W, A);
        k_gemm<<<256, 512, 0, stream>>>(A, W, G, VT);
        k_attn<<<1024, 256, 0, stream>>>(A, G, VT, lng, lnb, (float*)d_out);
    } else {
        k_prep<<<256, 256, 0, stream>>>(H, Z, Whk, Whv, Wzk, Wzv, Wq, Wout, W, A);
        k_batch_fb<<<256, 1024, 0, stream>>>(H, Z, W, lng, lnb, (float*)d_out);
    }
}

// Round 8
// 209.169 us; speedup vs baseline: 1.0836x; 1.0836x over previous
//
#include <hip/hip_runtime.h>
#include <hip/hip_bf16.h>
#include <cstdint>
#include <cstddef>

typedef __bf16 bf16_t;
typedef __bf16 bf16x8 __attribute__((ext_vector_type(8)));
typedef __bf16 bf16x4 __attribute__((ext_vector_type(4)));
typedef float f32x4 __attribute__((ext_vector_type(4)));

#define MFMA16(a, b, c) __builtin_amdgcn_mfma_f32_16x16x32_bf16((a), (b), (c), 0, 0, 0)

__device__ __forceinline__ bf16x8 ld8f(const float* p) {
    f32x4 a = *reinterpret_cast<const f32x4*>(p);
    f32x4 b = *reinterpret_cast<const f32x4*>(p + 4);
    bf16x8 r;
    r[0] = (bf16_t)a[0]; r[1] = (bf16_t)a[1]; r[2] = (bf16_t)a[2]; r[3] = (bf16_t)a[3];
    r[4] = (bf16_t)b[0]; r[5] = (bf16_t)b[1]; r[6] = (bf16_t)b[2]; r[7] = (bf16_t)b[3];
    return r;
}
__device__ __forceinline__ bf16x8 ldg8(const bf16_t* p) {
    return *reinterpret_cast<const bf16x8*>(p);
}
// async global->LDS DMA, 16B/lane; lds dest = uniform base + lane*16B
__device__ __forceinline__ void gload_lds16(const bf16_t* g, bf16_t* l) {
    __builtin_amdgcn_global_load_lds((const __attribute__((address_space(1))) void*)g,
                                     (__attribute__((address_space(3))) void*)l, 16, 0, 0);
}

// ---------------------------------------------------------------------------
// K0 k_prep: REVERTED to R6 layout (the 210.4us-total config):
//   blocks 0..255   = fused-weight GEMM (launched FIRST -> fully overlaps
//                     the pack; R7 proved tail-placement serializes instead)
//   blocks 256..8447 = pack/convert H,Z f32 -> A bf16[16384][1024]
// Weight GEMM keeps the depth-2 register prefetch (bit-identical W).
// ---------------------------------------------------------------------------
__global__ __launch_bounds__(256) void k_prep(
    const float* __restrict__ H, const float* __restrict__ Z,
    const float* __restrict__ Whk, const float* __restrict__ Whv,
    const float* __restrict__ Wzk, const float* __restrict__ Wzv,
    const float* __restrict__ Wq,  const float* __restrict__ Wout,
    bf16_t* __restrict__ W, bf16_t* __restrict__ A)
{
    const int tid = threadIdx.x;
    if (blockIdx.x >= 256) {
        const int row = (blockIdx.x - 256) * 2 + (tid >> 7);
        const int c8 = (tid & 127) * 8;
        const float* src = (c8 < 512) ? (H + (size_t)row * 512 + c8)
                                      : (Z + (size_t)row * 512 + (c8 - 512));
        *reinterpret_cast<bf16x8*>(A + (size_t)row * 1024 + c8) = ld8f(src);
        return;
    }
    __shared__ bf16_t LA[64][40];
    __shared__ bf16_t LB[64][40];
    const int lane = tid & 63, wid = tid >> 6;
    const int L15 = lane & 15, qd = lane >> 4;
    const int quad = blockIdx.x & 3, tile = blockIdx.x >> 2;
    const int ti = (tile >> 3) * 64, tj = (tile & 7) * 64;
    const float RS = 0.04419417382415922f;  // 1/sqrt(512)

    const float* Lp; const float* Rp; int orow, ocol; float scale; int transL;
    switch (quad) {
        case 0:  Lp = Wq;           Rp = Whk; orow = 0;   ocol = 0;   scale = RS;  transL = 1; break;
        case 1:  Lp = Wout;         Rp = Whv; orow = 512; ocol = 0;   scale = 1.f; transL = 0; break;
        case 2:  Lp = Wq + 524288;  Rp = Wzk; orow = 0;   ocol = 512; scale = RS;  transL = 1; break;
        default: Lp = Wout + 1024;  Rp = Wzv; orow = 512; ocol = 512; scale = 1.f; transL = 0; break;
    }

    const int li  = tid & 63;
    const int lk8 = (tid >> 6) * 8;
    const int di  = tid >> 2;
    const int dk0 = (tid & 3) * 8;

    float fa0[8], fb0[8], fa1[8], fb1[8];
    auto loadT = [&](int kc, float* fa, float* fb) {
        const int k0 = kc * 32;
        if (transL) {
#pragma unroll
            for (int j = 0; j < 8; j++)
                fa[j] = Lp[(size_t)(k0 + lk8 + j) * 512 + ti + li];
        } else {
            const float* p = Lp + (size_t)(ti + di) * 2048 + k0 + dk0;
            f32x4 v0 = *reinterpret_cast<const f32x4*>(p);
            f32x4 v1 = *reinterpret_cast<const f32x4*>(p + 4);
#pragma unroll
            for (int j = 0; j < 4; j++) { fa[j] = v0[j]; fa[4 + j] = v1[j]; }
        }
#pragma unroll
        for (int j = 0; j < 8; j++)
            fb[j] = Rp[(size_t)(k0 + lk8 + j) * 512 + tj + li];
    };

    f32x4 acc[4];
#pragma unroll
    for (int t = 0; t < 4; t++) acc[t] = (f32x4){0.f, 0.f, 0.f, 0.f};

    loadT(0, fa0, fb0);
    loadT(1, fa1, fb1);

#define WSTEP(FA, FB, KPRE) { \
        __syncthreads(); \
        bf16x8 pa, pb; \
        _Pragma("unroll") \
        for (int j = 0; j < 8; j++) { pa[j] = (bf16_t)FA[j]; pb[j] = (bf16_t)FB[j]; } \
        if (transL) *reinterpret_cast<bf16x8*>(&LA[li][lk8]) = pa; \
        else        *reinterpret_cast<bf16x8*>(&LA[di][dk0]) = pa; \
        *reinterpret_cast<bf16x8*>(&LB[li][lk8]) = pb; \
        __syncthreads(); \
        if ((KPRE) < 32) loadT((KPRE), FA, FB); \
        bf16x8 afr = *reinterpret_cast<bf16x8*>(&LA[wid * 16 + L15][qd * 8]); \
        _Pragma("unroll") \
        for (int t = 0; t < 4; t++) { \
            bf16x8 bfr = *reinterpret_cast<bf16x8*>(&LB[t * 16 + L15][qd * 8]); \
            acc[t] = MFMA16(afr, bfr, acc[t]); \
        } }

#pragma unroll 1
    for (int kc = 0; kc < 32; kc += 2) {
        WSTEP(fa0, fb0, kc + 2);
        WSTEP(fa1, fb1, kc + 3);
    }
#undef WSTEP

#pragma unroll
    for (int t = 0; t < 4; t++) {
        int col = ocol + tj + t * 16 + L15;
#pragma unroll
        for (int r = 0; r < 4; r++) {
            int row = orow + ti + wid * 16 + qd * 4 + r;
            W[(size_t)row * 1024 + col] = (bf16_t)(acc[t][r] * scale);
        }
    }
}

// ---------------------------------------------------------------------------
// K2 k_gemm: vmcnt(6) schedule + cross-tile read-ahead (kept from R7 —
// unattributed there because k_prep masked it; this round attributes it).
// Next tile's A0/B0 fragment reads moved to current tile's P3, after the
// boundary vmcnt (whole next tile provably in LDS). MFMA order unchanged.
// ---------------------------------------------------------------------------
__global__ __launch_bounds__(512, 2) void k_gemm(
    const bf16_t* __restrict__ A, const bf16_t* __restrict__ W,
    bf16_t* __restrict__ G, bf16_t* __restrict__ VT)
{
    __shared__ bf16_t LA[2][256 * 64];
    __shared__ bf16_t LB[2][256 * 64];
    const int tid = threadIdx.x, lane = tid & 63, wid = tid >> 6;
    const int L15 = lane & 15, qd = lane >> 4;
    // XCD = bid&7 (round-robin dispatch); blocks sharing mb land on same XCD.
    const int mb = (blockIdx.x & 7) + (((blockIdx.x >> 3) & 7) << 3);
    const int nb = blockIdx.x >> 6;
    const int m0 = mb * 256, n0 = nb * 256;
    const int wm = wid >> 2, wn = wid & 3;

    // ---- staging addressing ----
    const int si = tid >> 3;                           // 0..63
    const int gs = ((tid & 7) ^ (si & 7)) * 8;         // swizzled src chunk
    const int rowB = (si & 31) + ((si >> 5) << 6);     // B stripe row base
    const bf16_t* Ag = A + (size_t)(m0 + si) * 1024 + gs;
    const bf16_t* Wg = W + (size_t)(n0 + rowB) * 1024 + gs;
    const int loA = tid * 8;                                             // elems
    const int loB = ((si & 31) << 6) + ((si >> 5) << 12) + ((tid & 7) << 3);

    // ---- fragment read offsets (swizzled) ----
    const int r7 = L15 & 7;
    const int ea0 = (qd ^ r7) * 8;
    const int ea1 = ((4 + qd) ^ r7) * 8;
    const int arow = (wm * 128 + L15) * 64;            // + mh*4096 + mt*1024
    const int brow = (wn * 64 + L15) * 64;             // + nh*2048 + nt*1024

    f32x4 acc[8][4];
#pragma unroll
    for (int mt = 0; mt < 8; mt++)
#pragma unroll
        for (int nt = 0; nt < 4; nt++) acc[mt][nt] = (f32x4){0.f, 0.f, 0.f, 0.f};

    bf16x8 af[4][2];        // current mh's A frags
    bf16x8 bfr[2][2][2];    // all B frags [nh][nt][ks]

#define STG_U0(B, ktn) { gload_lds16(Ag + (size_t)(ktn) * 64,          &LA[B][loA]); \
                         gload_lds16(Ag + (size_t)(ktn) * 64 + 131072, &LA[B][8192 + loA]); }
#define STG_U2(B, ktn) { gload_lds16(Ag + (size_t)(ktn) * 64 + 65536,  &LA[B][4096 + loA]); \
                         gload_lds16(Ag + (size_t)(ktn) * 64 + 196608, &LA[B][12288 + loA]); }
#define STG_U3(B, ktn) { gload_lds16(Wg + (size_t)(ktn) * 64,          &LB[B][loB]); \
                         gload_lds16(Wg + (size_t)(ktn) * 64 + 131072, &LB[B][8192 + loB]); }
#define STG_U1(B, ktn) { gload_lds16(Wg + (size_t)(ktn) * 64 + 32768,  &LB[B][2048 + loB]); \
                         gload_lds16(Wg + (size_t)(ktn) * 64 + 163840, &LB[B][10240 + loB]); }
#define LDA(B, mh) { _Pragma("unroll") for (int mt = 0; mt < 4; mt++) { \
        const bf16_t* p_ = &LA[B][arow + (mh) * 4096 + mt * 1024]; \
        af[mt][0] = *reinterpret_cast<const bf16x8*>(p_ + ea0); \
        af[mt][1] = *reinterpret_cast<const bf16x8*>(p_ + ea1); } }
#define LDB(B, nh) { _Pragma("unroll") for (int nt = 0; nt < 2; nt++) { \
        const bf16_t* p_ = &LB[B][brow + (nh) * 2048 + nt * 1024]; \
        bfr[nh][nt][0] = *reinterpret_cast<const bf16x8*>(p_ + ea0); \
        bfr[nh][nt][1] = *reinterpret_cast<const bf16x8*>(p_ + ea1); } }
#define MMAQ(mh, nh) { _Pragma("unroll") for (int mt = 0; mt < 4; mt++) \
        _Pragma("unroll") for (int nt = 0; nt < 2; nt++) { \
            acc[(mh)*4+mt][(nh)*2+nt] = MFMA16(af[mt][0], bfr[nh][nt][0], acc[(mh)*4+mt][(nh)*2+nt]); \
            acc[(mh)*4+mt][(nh)*2+nt] = MFMA16(af[mt][1], bfr[nh][nt][1], acc[(mh)*4+mt][(nh)*2+nt]); } }
#define BARX() __builtin_amdgcn_s_barrier()
#define PR1() __builtin_amdgcn_s_setprio(1)
#define PR0() __builtin_amdgcn_s_setprio(0)
#define WAIT_LGKM() { asm volatile("s_waitcnt lgkmcnt(0)" ::: "memory"); \
                      __builtin_amdgcn_sched_barrier(0); }
#define VMC6() { asm volatile("s_waitcnt vmcnt(6)" ::: "memory"); \
                 __builtin_amdgcn_sched_barrier(0); }
#define VMC0() { asm volatile("s_waitcnt vmcnt(0)" ::: "memory"); \
                 __builtin_amdgcn_sched_barrier(0); }
#define VMNONE() {}

    // TILE(B = buffer of tile t, S3 = stage U3(kt1), SN = stage U0/U1/U2(kt2),
    //      RA = read-ahead next tile's A0/B0 after the boundary wait)
#define TILE(B, S3, SN, kt1, kt2, VMW, RA) { \
        /* P0: frags A0,B0 pre-read at previous P3 */ \
        if (S3) STG_U3((B) ^ 1, kt1); \
        BARX(); WAIT_LGKM(); PR1(); MMAQ(0, 0); PR0(); BARX(); \
        /* P1 */ LDB(B, 1); \
        if (SN) STG_U0(B, kt2); \
        BARX(); WAIT_LGKM(); PR1(); MMAQ(0, 1); PR0(); BARX(); \
        /* P2 */ LDA(B, 1); \
        if (SN) STG_U1(B, kt2); \
        BARX(); WAIT_LGKM(); PR1(); MMAQ(1, 0); PR0(); BARX(); \
        /* P3 */ \
        if (SN) STG_U2(B, kt2); \
        BARX(); PR1(); MMAQ(1, 1); PR0(); \
        VMW; \
        if (RA) { LDA((B) ^ 1, 0); LDB((B) ^ 1, 0); } \
        BARX(); }

    // prologue: tile0 complete + tile1 U0,U1,U2; vmcnt(6) completes tile 0;
    // then pre-read tile 0's A0/B0 (waited at tile 0 P0).
    STG_U0(0, 0); STG_U1(0, 0); STG_U2(0, 0); STG_U3(0, 0);
    STG_U0(1, 1); STG_U1(1, 1); STG_U2(1, 1);
    VMC6(); BARX();
    LDA(0, 0); LDB(0, 0);

    for (int t = 0; t < 14; t += 2) {
        TILE(0, 1, 1, t + 1, t + 2, VMC6(), 1);
        TILE(1, 1, 1, t + 2, t + 3, VMC6(), 1);
    }
    TILE(0, 1, 0, 15, 0, VMC0(), 1);   // tile 14: stage U3(15), drain, pre-read 15
    TILE(1, 0, 0, 0, 0, VMNONE(), 0);  // tile 15: no staging, no wait

#undef TILE
#undef STG_U0
#undef STG_U1
#undef STG_U2
#undef STG_U3
#undef LDA
#undef LDB
#undef MMAQ

    if (nb < 2) {
#pragma unroll
        for (int mt = 0; mt < 8; mt++) {
            int mrow = m0 + wm * 128 + mt * 16 + qd * 4;
#pragma unroll
            for (int nt = 0; nt < 4; nt++) {
                int j = n0 + wn * 64 + nt * 16 + L15;
#pragma unroll
                for (int r = 0; r < 4; r++)
                    G[(size_t)(mrow + r) * 512 + j] = (bf16_t)acc[mt][nt][r];
            }
        }
    } else {
#pragma unroll
        for (int mt = 0; mt < 8; mt++) {
            int mrow = m0 + wm * 128 + mt * 16 + qd * 4;
            int n = mrow >> 6, kl = mrow & 63;
#pragma unroll
            for (int nt = 0; nt < 4; nt++) {
                int dloc = (n0 - 512) + wn * 64 + nt * 16 + L15;
                bf16x4 pk;
#pragma unroll
                for (int r = 0; r < 4; r++) pk[r] = (bf16_t)acc[mt][nt][r];
                *reinterpret_cast<bf16x4*>(&VT[(size_t)n * 32768 + (size_t)dloc * 64 + kl]) = pk;
            }
        }
    }
}

// ---------------------------------------------------------------------------
// K3 k_attn: unchanged (1024-block version from the best-measured run).
// ---------------------------------------------------------------------------
__global__ __launch_bounds__(256) void k_attn(
    const bf16_t* __restrict__ A,
    const bf16_t* __restrict__ G, const bf16_t* __restrict__ VT,
    const float* __restrict__ lng, const float* __restrict__ lnb,
    float* __restrict__ out)
{
    __shared__ float  Sl[16][68];
    __shared__ bf16_t Sp[16][72];
    __shared__ float  Rs[4][16];
    __shared__ float  Rq[4][16];
    const int n = blockIdx.x & 255, ks4 = blockIdx.x >> 8;
    const int tid = threadIdx.x, lane = tid & 63, w = tid >> 6;
    const int L15 = lane & 15, qd = lane >> 4;
    const bf16_t* Gb = G + (size_t)n * 32768 + (size_t)(ks4 * 16) * 512;
    const bf16_t* Vb = VT + (size_t)n * 32768;
    const bf16_t* Ab = A + (size_t)n * 64 * 1024;

    bf16x8 bv[2][8];
#pragma unroll
    for (int kq = 0; kq < 2; kq++)
#pragma unroll
        for (int dt = 0; dt < 8; dt++)
            bv[kq][dt] = ldg8(Vb + (size_t)(w * 128 + dt * 16 + L15) * 64 + kq * 32 + qd * 8);

    {   // logits[16 k-rows][q-tile w], two independent MFMA chains
        f32x4 lg0 = (f32x4){0.f, 0.f, 0.f, 0.f};
        f32x4 lg1 = (f32x4){0.f, 0.f, 0.f, 0.f};
        const bf16_t* ga = Gb + (size_t)L15 * 512 + qd * 8;
        const bf16_t* ab = Ab + (size_t)(w * 16 + L15) * 1024 + qd * 8;
#pragma unroll
        for (int ks = 0; ks < 16; ks += 2) {
            lg0 = MFMA16(ldg8(ga + ks * 32),      ldg8(ab + ks * 32),      lg0);
            lg1 = MFMA16(ldg8(ga + ks * 32 + 32), ldg8(ab + ks * 32 + 32), lg1);
        }
        f32x4 lg = lg0 + lg1;
#pragma unroll
        for (int r = 0; r < 4; r++)
            Sl[qd * 4 + r][w * 16 + L15] = lg[r];
    }
    __syncthreads();
    {   // softmax over q (64): 16 threads/row, 4 cols each
        int row = tid >> 4, c0 = (tid & 15) * 4;
        float4 v = *reinterpret_cast<float4*>(&Sl[row][c0]);
        float mx = fmaxf(fmaxf(v.x, v.y), fmaxf(v.z, v.w));
#pragma unroll
        for (int m = 1; m < 16; m <<= 1) mx = fmaxf(mx, __shfl_xor(mx, m));
        float e0 = __expf(v.x - mx), e1 = __expf(v.y - mx);
        float e2 = __expf(v.z - mx), e3 = __expf(v.w - mx);
        float s = e0 + e1 + e2 + e3;
#pragma unroll
        for (int m = 1; m < 16; m <<= 1) s += __shfl_xor(s, m);
        float inv = 1.0f / s;
        bf16x4 p;
        p[0] = (bf16_t)(e0 * inv); p[1] = (bf16_t)(e1 * inv);
        p[2] = (bf16_t)(e2 * inv); p[3] = (bf16_t)(e3 * inv);
        *reinterpret_cast<bf16x4*>(&Sp[row][c0]) = p;
    }
    __syncthreads();

    f32x4 acc[8];
#pragma unroll
    for (int dt = 0; dt < 8; dt++) acc[dt] = (f32x4){0.f, 0.f, 0.f, 0.f};
#pragma unroll
    for (int kq = 0; kq < 2; kq++) {
        bf16x8 ap = *reinterpret_cast<bf16x8*>(&Sp[L15][kq * 32 + qd * 8]);
#pragma unroll
        for (int dt = 0; dt < 8; dt++)
            acc[dt] = MFMA16(ap, bv[kq][dt], acc[dt]);
    }
    float s4[4] = {0.f, 0.f, 0.f, 0.f}, ss4[4] = {0.f, 0.f, 0.f, 0.f};
#pragma unroll
    for (int dt = 0; dt < 8; dt++)
#pragma unroll
        for (int r = 0; r < 4; r++) { float x = acc[dt][r]; s4[r] += x; ss4[r] += x * x; }
#pragma unroll
    for (int m = 1; m < 16; m <<= 1)
#pragma unroll
        for (int r = 0; r < 4; r++) {
            s4[r]  += __shfl_xor(s4[r], m);
            ss4[r] += __shfl_xor(ss4[r], m);
        }
    if (L15 == 0)
#pragma unroll
        for (int r = 0; r < 4; r++) {
            int row = qd * 4 + r;
            Rs[w][row] = s4[r];
            Rq[w][row] = ss4[r];
        }
    __syncthreads();
    float mean[4], rstd[4];
#pragma unroll
    for (int r = 0; r < 4; r++) {
        int row = qd * 4 + r;
        float S = Rs[0][row] + Rs[1][row] + Rs[2][row] + Rs[3][row];
        float Q = Rq[0][row] + Rq[1][row] + Rq[2][row] + Rq[3][row];
        float mu = S * (1.f / 512.f);
        float var = Q * (1.f / 512.f) - mu * mu;
        mean[r] = mu;
        rstd[r] = rsqrtf(var + 1e-5f);
    }
    float* ob = out + (size_t)n * 32768 + (size_t)(ks4 * 16) * 512;
#pragma unroll
    for (int dt = 0; dt < 8; dt++) {
        int col = w * 128 + dt * 16 + L15;
        float gg = lng[col], bb = lnb[col];
#pragma unroll
        for (int r = 0; r < 4; r++) {
            int row = qd * 4 + r;
            ob[(size_t)row * 512 + col] = (acc[dt][r] - mean[r]) * rstd[r] * gg + bb;
        }
    }
}

// ---------------------------------------------------------------------------
// Fallback fused per-batch kernel — only if ws too small.
// ---------------------------------------------------------------------------
__global__ __launch_bounds__(1024) void k_batch_fb(
    const float* __restrict__ H, const float* __restrict__ Z,
    const bf16_t* __restrict__ W,
    const float* __restrict__ lng, const float* __restrict__ lnb,
    float* __restrict__ out)
{
    __shared__ __align__(16) char lds_raw[48128];
    bf16_t* lds_bf = (bf16_t*)lds_raw;
    float*  lds_f  = (float*)lds_raw;
    bf16_t* Gbuf = lds_bf;
    float*  Sl   = lds_f;
    bf16_t* VTl  = lds_bf;
    bf16_t* Sp   = lds_bf + 18432;
    float*  Rs   = lds_f + 11520;
    float*  Rq   = lds_f + 11776;

    const int n = blockIdx.x;
    const int tid = threadIdx.x, lane = tid & 63, w = tid >> 6;
    const int L15 = lane & 15, qd = lane >> 4;
    const int strip = w & 3, grp = w >> 2;
    const float* Hb = H + (size_t)n * 32768;
    const float* Zb = Z + (size_t)n * 32768;

    f32x4 a1 = (f32x4){0.f, 0.f, 0.f, 0.f};
    for (int hf = 0; hf < 2; hf++) {
        f32x4 ga[4];
#pragma unroll
        for (int mt = 0; mt < 4; mt++) ga[mt] = (f32x4){0.f, 0.f, 0.f, 0.f};
        const bf16_t* wrow = W + (size_t)(hf * 256 + w * 16 + L15) * 1024;
#pragma unroll 4
        for (int kc = 0; kc < 16; kc++) {
            const int ko = kc * 32 + qd * 8;
            bf16x8 bh = ldg8(wrow + ko);
            bf16x8 bz = ldg8(wrow + 512 + ko);
#pragma unroll
            for (int mt = 0; mt < 4; mt++) {
                bf16x8 ah = ld8f(Hb + (size_t)(mt * 16 + L15) * 512 + ko);
                bf16x8 az = ld8f(Zb + (size_t)(mt * 16 + L15) * 512 + ko);
                ga[mt] = MFMA16(ah, bh, ga[mt]);
                ga[mt] = MFMA16(az, bz, ga[mt]);
            }
        }
        __syncthreads();
#pragma unroll
        for (int mt = 0; mt < 4; mt++)
#pragma unroll
            for (int r = 0; r < 4; r++)
                Gbuf[(size_t)(mt * 16 + qd * 4 + r) * 264 + w * 16 + L15] = (bf16_t)ga[mt][r];
        __syncthreads();
#pragma unroll
        for (int kcf = 0; kcf < 8; kcf++) {
            bf16x8 af = *reinterpret_cast<bf16x8*>(
                &Gbuf[(size_t)(strip * 16 + L15) * 264 + kcf * 32 + qd * 8]);
            bf16x8 bq = ld8f(Hb + (size_t)(grp * 16 + L15) * 512 + hf * 256 + kcf * 32 + qd * 8);
            a1 = MFMA16(af, bq, a1);
        }
    }
    __syncthreads();
#pragma unroll
    for (int r = 0; r < 4; r++)
        Sl[(size_t)(strip * 16 + qd * 4 + r) * 64 + grp * 16 + L15] = a1[r];
    __syncthreads();
    {
        int row = tid >> 4, c0 = (tid & 15) * 4;
        float4 v = *reinterpret_cast<float4*>(&Sl[(size_t)row * 64 + c0]);
        float mx = fmaxf(fmaxf(v.x, v.y), fmaxf(v.z, v.w));
#pragma unroll
        for (int m = 1; m < 16; m <<= 1) mx = fmaxf(mx, __shfl_xor(mx, m));
        float e0 = __expf(v.x - mx), e1 = __expf(v.y - mx);
        float e2 = __expf(v.z - mx), e3 = __expf(v.w - mx);
        float s = e0 + e1 + e2 + e3;
#pragma unroll
        for (int m = 1; m < 16; m <<= 1) s += __shfl_xor(s, m);
        float inv = 1.0f / s;
        bf16x4 p;
        p[0] = (bf16_t)(e0 * inv); p[1] = (bf16_t)(e1 * inv);
        p[2] = (bf16_t)(e2 * inv); p[3] = (bf16_t)(e3 * inv);
        *reinterpret_cast<bf16x4*>(&Sp[(size_t)row * 72 + c0]) = p;
    }
    __syncthreads();

    f32x4 acc[8];
#pragma unroll
    for (int j = 0; j < 8; j++) acc[j] = (f32x4){0.f, 0.f, 0.f, 0.f};
    for (int hf2 = 0; hf2 < 2; hf2++) {
        f32x4 va[4];
#pragma unroll
        for (int mt = 0; mt < 4; mt++) va[mt] = (f32x4){0.f, 0.f, 0.f, 0.f};
        const bf16_t* wrow = W + (size_t)(512 + hf2 * 256 + w * 16 + L15) * 1024;
#pragma unroll 4
        for (int kc = 0; kc < 16; kc++) {
            const int ko = kc * 32 + qd * 8;
            bf16x8 bh = ldg8(wrow + ko);
            bf16x8 bz = ldg8(wrow + 512 + ko);
#pragma unroll
            for (int mt = 0; mt < 4; mt++) {
                bf16x8 ah = ld8f(Hb + (size_t)(mt * 16 + L15) * 512 + ko);
                bf16x8 az = ld8f(Zb + (size_t)(mt * 16 + L15) * 512 + ko);
                va[mt] = MFMA16(ah, bh, va[mt]);
                va[mt] = MFMA16(az, bz, va[mt]);
            }
        }
#pragma unroll
        for (int mt = 0; mt < 4; mt++) {
            bf16x4 pk;
#pragma unroll
            for (int r = 0; r < 4; r++) pk[r] = (bf16_t)va[mt][r];
            *reinterpret_cast<bf16x4*>(&VTl[(size_t)(w * 16 + L15) * 72 + mt * 16 + qd * 4]) = pk;
        }
        __syncthreads();
#pragma unroll
        for (int kcq = 0; kcq < 2; kcq++) {
            bf16x8 ap = *reinterpret_cast<bf16x8*>(
                &Sp[(size_t)(strip * 16 + L15) * 72 + kcq * 32 + qd * 8]);
#pragma unroll
            for (int dt = 0; dt < 4; dt++) {
                bf16x8 bvl = *reinterpret_cast<bf16x8*>(
                    &VTl[(size_t)(grp * 64 + dt * 16 + L15) * 72 + kcq * 32 + qd * 8]);
                acc[hf2 * 4 + dt] = MFMA16(ap, bvl, acc[hf2 * 4 + dt]);
            }
        }
        __syncthreads();
    }
    float s4[4] = {0.f, 0.f, 0.f, 0.f}, ss4[4] = {0.f, 0.f, 0.f, 0.f};
#pragma unroll
    for (int j = 0; j < 8; j++)
#pragma unroll
        for (int r = 0; r < 4; r++) { float x = acc[j][r]; s4[r] += x; ss4[r] += x * x; }
#pragma unroll
    for (int m = 1; m < 16; m <<= 1)
#pragma unroll
        for (int r = 0; r < 4; r++) {
            s4[r]  += __shfl_xor(s4[r], m);
            ss4[r] += __shfl_xor(ss4[r], m);
        }
    if (L15 == 0)
#pragma unroll
        for (int r = 0; r < 4; r++) {
            int row = strip * 16 + qd * 4 + r;
            Rs[grp * 64 + row] = s4[r];
            Rq[grp * 64 + row] = ss4[r];
        }
    __syncthreads();
    float mean[4], rstd[4];
#pragma unroll
    for (int r = 0; r < 4; r++) {
        int row = strip * 16 + qd * 4 + r;
        float S = Rs[row] + Rs[64 + row] + Rs[128 + row] + Rs[192 + row];
        float Q = Rq[row] + Rq[64 + row] + Rq[128 + row] + Rq[192 + row];
        float mu = S * (1.f / 512.f);
        float var = Q * (1.f / 512.f) - mu * mu;
        mean[r] = mu;
        rstd[r] = rsqrtf(var + 1e-5f);
    }
#pragma unroll
    for (int j = 0; j < 8; j++) {
        int col = (j >> 2) * 256 + grp * 64 + (j & 3) * 16 + L15;
        float gg = lng[col], bb = lnb[col];
#pragma unroll
        for (int r = 0; r < 4; r++) {
            int row = strip * 16 + qd * 4 + r;
            out[(size_t)n * 32768 + (size_t)row * 512 + col] =
                (acc[j][r] - mean[r]) * rstd[r] * gg + bb;
        }
    }
}

extern "C" void kernel_launch(void* const* d_in, const int* in_sizes, int n_in,
                              void* d_out, int out_size, void* d_ws, size_t ws_size,
                              hipStream_t stream) {
    const float* H    = (const float*)d_in[0];
    const float* Z    = (const float*)d_in[1];
    const float* Whk  = (const float*)d_in[2];
    const float* Whv  = (const float*)d_in[3];
    const float* Wzk  = (const float*)d_in[4];
    const float* Wzv  = (const float*)d_in[5];
    const float* Wq   = (const float*)d_in[6];
    const float* Wout = (const float*)d_in[7];
    const float* lng  = (const float*)d_in[8];
    const float* lnb  = (const float*)d_in[9];

    bf16_t* W  = (bf16_t*)d_ws;            // [1024][1024]    2 MiB
    bf16_t* A  = W + 1024 * 1024;          // [16384][1024]  32 MiB
    bf16_t* G  = A + (size_t)16384 * 1024; // [16384][512]   16 MiB
    bf16_t* VT = G + (size_t)16384 * 512;  // [256][512][64] 16 MiB
    const size_t need = ((size_t)1024 * 1024 + (size_t)16384 * 1024 +
                         (size_t)16384 * 512 + (size_t)256 * 512 * 64) * 2;

    if (ws_size >= need) {
        k_prep<<<8448, 256, 0, stream>>>(H, Z, Whk, Whv, Wzk, Wzv, Wq, Wout, W, A);
        k_gemm<<<256, 512, 0, stream>>>(A, W, G, VT);
        k_attn<<<1024, 256, 0, stream>>>(A, G, VT, lng, lnb, (float*)d_out);
    } else {
        k_prep<<<256, 256, 0, stream>>>(H, Z, Whk, Whv, Wzk, Wzv, Wq, Wout, W, A);
        k_batch_fb<<<256, 1024, 0, stream>>>(H, Z, W, lng, lnb, (float*)d_out);
    }
}

// Round 9
// 204.664 us; speedup vs baseline: 1.1075x; 1.0220x over previous
//
#include <hip/hip_runtime.h>
#include <hip/hip_bf16.h>
#include <cstdint>
#include <cstddef>

typedef __bf16 bf16_t;
typedef __bf16 bf16x8 __attribute__((ext_vector_type(8)));
typedef __bf16 bf16x4 __attribute__((ext_vector_type(4)));
typedef float f32x4 __attribute__((ext_vector_type(4)));

#define MFMA16(a, b, c) __builtin_amdgcn_mfma_f32_16x16x32_bf16((a), (b), (c), 0, 0, 0)

__device__ __forceinline__ bf16x8 ld8f(const float* p) {
    f32x4 a = *reinterpret_cast<const f32x4*>(p);
    f32x4 b = *reinterpret_cast<const f32x4*>(p + 4);
    bf16x8 r;
    r[0] = (bf16_t)a[0]; r[1] = (bf16_t)a[1]; r[2] = (bf16_t)a[2]; r[3] = (bf16_t)a[3];
    r[4] = (bf16_t)b[0]; r[5] = (bf16_t)b[1]; r[6] = (bf16_t)b[2]; r[7] = (bf16_t)b[3];
    return r;
}
__device__ __forceinline__ bf16x8 ldg8(const bf16_t* p) {
    return *reinterpret_cast<const bf16x8*>(p);
}
// async global->LDS DMA, 16B/lane; lds dest = uniform base + lane*16B
__device__ __forceinline__ void gload_lds16(const bf16_t* g, bf16_t* l) {
    __builtin_amdgcn_global_load_lds((const __attribute__((address_space(1))) void*)g,
                                     (__attribute__((address_space(3))) void*)l, 16, 0, 0);
}

// ---------------------------------------------------------------------------
// K0 k_prep (R6 layout, the proven-best config):
//   blocks 0..255   = fused-weight GEMM (launched FIRST -> overlaps the pack)
//   blocks 256..8447 = pack/convert H,Z f32 -> A bf16[16384][1024]
// SINGLE DELTA vs R8: wgemm register prefetch depth 2 -> 4 (fa0-3/fb0-3,
// statically indexed). Loads for kc+4 issued at kc -> ~4 iters (~1500-2000cy)
// of latency slack, matching the pack-congested HBM latency. Same loads,
// same convert/MFMA order -> W bit-identical.
// ---------------------------------------------------------------------------
__global__ __launch_bounds__(256) void k_prep(
    const float* __restrict__ H, const float* __restrict__ Z,
    const float* __restrict__ Whk, const float* __restrict__ Whv,
    const float* __restrict__ Wzk, const float* __restrict__ Wzv,
    const float* __restrict__ Wq,  const float* __restrict__ Wout,
    bf16_t* __restrict__ W, bf16_t* __restrict__ A)
{
    const int tid = threadIdx.x;
    if (blockIdx.x >= 256) {
        const int row = (blockIdx.x - 256) * 2 + (tid >> 7);
        const int c8 = (tid & 127) * 8;
        const float* src = (c8 < 512) ? (H + (size_t)row * 512 + c8)
                                      : (Z + (size_t)row * 512 + (c8 - 512));
        *reinterpret_cast<bf16x8*>(A + (size_t)row * 1024 + c8) = ld8f(src);
        return;
    }
    __shared__ bf16_t LA[64][40];
    __shared__ bf16_t LB[64][40];
    const int lane = tid & 63, wid = tid >> 6;
    const int L15 = lane & 15, qd = lane >> 4;
    const int quad = blockIdx.x & 3, tile = blockIdx.x >> 2;
    const int ti = (tile >> 3) * 64, tj = (tile & 7) * 64;
    const float RS = 0.04419417382415922f;  // 1/sqrt(512)

    const float* Lp; const float* Rp; int orow, ocol; float scale; int transL;
    switch (quad) {
        case 0:  Lp = Wq;           Rp = Whk; orow = 0;   ocol = 0;   scale = RS;  transL = 1; break;
        case 1:  Lp = Wout;         Rp = Whv; orow = 512; ocol = 0;   scale = 1.f; transL = 0; break;
        case 2:  Lp = Wq + 524288;  Rp = Wzk; orow = 0;   ocol = 512; scale = RS;  transL = 1; break;
        default: Lp = Wout + 1024;  Rp = Wzv; orow = 512; ocol = 512; scale = 1.f; transL = 0; break;
    }

    const int li  = tid & 63;
    const int lk8 = (tid >> 6) * 8;
    const int di  = tid >> 2;
    const int dk0 = (tid & 3) * 8;

    float fa0[8], fb0[8], fa1[8], fb1[8], fa2[8], fb2[8], fa3[8], fb3[8];
    auto loadT = [&](int kc, float* fa, float* fb) {
        const int k0 = kc * 32;
        if (transL) {
#pragma unroll
            for (int j = 0; j < 8; j++)
                fa[j] = Lp[(size_t)(k0 + lk8 + j) * 512 + ti + li];
        } else {
            const float* p = Lp + (size_t)(ti + di) * 2048 + k0 + dk0;
            f32x4 v0 = *reinterpret_cast<const f32x4*>(p);
            f32x4 v1 = *reinterpret_cast<const f32x4*>(p + 4);
#pragma unroll
            for (int j = 0; j < 4; j++) { fa[j] = v0[j]; fa[4 + j] = v1[j]; }
        }
#pragma unroll
        for (int j = 0; j < 8; j++)
            fb[j] = Rp[(size_t)(k0 + lk8 + j) * 512 + tj + li];
    };

    f32x4 acc[4];
#pragma unroll
    for (int t = 0; t < 4; t++) acc[t] = (f32x4){0.f, 0.f, 0.f, 0.f};

    loadT(0, fa0, fb0);
    loadT(1, fa1, fb1);
    loadT(2, fa2, fb2);
    loadT(3, fa3, fb3);

#define WSTEP(FA, FB, KPRE) { \
        __syncthreads(); \
        bf16x8 pa, pb; \
        _Pragma("unroll") \
        for (int j = 0; j < 8; j++) { pa[j] = (bf16_t)FA[j]; pb[j] = (bf16_t)FB[j]; } \
        if (transL) *reinterpret_cast<bf16x8*>(&LA[li][lk8]) = pa; \
        else        *reinterpret_cast<bf16x8*>(&LA[di][dk0]) = pa; \
        *reinterpret_cast<bf16x8*>(&LB[li][lk8]) = pb; \
        __syncthreads(); \
        if ((KPRE) < 32) loadT((KPRE), FA, FB); \
        bf16x8 afr = *reinterpret_cast<bf16x8*>(&LA[wid * 16 + L15][qd * 8]); \
        _Pragma("unroll") \
        for (int t = 0; t < 4; t++) { \
            bf16x8 bfr = *reinterpret_cast<bf16x8*>(&LB[t * 16 + L15][qd * 8]); \
            acc[t] = MFMA16(afr, bfr, acc[t]); \
        } }

#pragma unroll 1
    for (int kc = 0; kc < 32; kc += 4) {
        WSTEP(fa0, fb0, kc + 4);
        WSTEP(fa1, fb1, kc + 5);
        WSTEP(fa2, fb2, kc + 6);
        WSTEP(fa3, fb3, kc + 7);
    }
#undef WSTEP

#pragma unroll
    for (int t = 0; t < 4; t++) {
        int col = ocol + tj + t * 16 + L15;
#pragma unroll
        for (int r = 0; r < 4; r++) {
            int row = orow + ti + wid * 16 + qd * 4 + r;
            W[(size_t)row * 1024 + col] = (bf16_t)(acc[t][r] * scale);
        }
    }
}

// ---------------------------------------------------------------------------
// K2 k_gemm: unchanged R8 text (vmcnt(6) schedule + cross-tile read-ahead,
// measured 44.0-44.9 us, MfmaUtil ~30).
// ---------------------------------------------------------------------------
__global__ __launch_bounds__(512, 2) void k_gemm(
    const bf16_t* __restrict__ A, const bf16_t* __restrict__ W,
    bf16_t* __restrict__ G, bf16_t* __restrict__ VT)
{
    __shared__ bf16_t LA[2][256 * 64];
    __shared__ bf16_t LB[2][256 * 64];
    const int tid = threadIdx.x, lane = tid & 63, wid = tid >> 6;
    const int L15 = lane & 15, qd = lane >> 4;
    // XCD = bid&7 (round-robin dispatch); blocks sharing mb land on same XCD.
    const int mb = (blockIdx.x & 7) + (((blockIdx.x >> 3) & 7) << 3);
    const int nb = blockIdx.x >> 6;
    const int m0 = mb * 256, n0 = nb * 256;
    const int wm = wid >> 2, wn = wid & 3;

    // ---- staging addressing ----
    const int si = tid >> 3;                           // 0..63
    const int gs = ((tid & 7) ^ (si & 7)) * 8;         // swizzled src chunk
    const int rowB = (si & 31) + ((si >> 5) << 6);     // B stripe row base
    const bf16_t* Ag = A + (size_t)(m0 + si) * 1024 + gs;
    const bf16_t* Wg = W + (size_t)(n0 + rowB) * 1024 + gs;
    const int loA = tid * 8;                                             // elems
    const int loB = ((si & 31) << 6) + ((si >> 5) << 12) + ((tid & 7) << 3);

    // ---- fragment read offsets (swizzled) ----
    const int r7 = L15 & 7;
    const int ea0 = (qd ^ r7) * 8;
    const int ea1 = ((4 + qd) ^ r7) * 8;
    const int arow = (wm * 128 + L15) * 64;            // + mh*4096 + mt*1024
    const int brow = (wn * 64 + L15) * 64;             // + nh*2048 + nt*1024

    f32x4 acc[8][4];
#pragma unroll
    for (int mt = 0; mt < 8; mt++)
#pragma unroll
        for (int nt = 0; nt < 4; nt++) acc[mt][nt] = (f32x4){0.f, 0.f, 0.f, 0.f};

    bf16x8 af[4][2];        // current mh's A frags
    bf16x8 bfr[2][2][2];    // all B frags [nh][nt][ks]

#define STG_U0(B, ktn) { gload_lds16(Ag + (size_t)(ktn) * 64,          &LA[B][loA]); \
                         gload_lds16(Ag + (size_t)(ktn) * 64 + 131072, &LA[B][8192 + loA]); }
#define STG_U2(B, ktn) { gload_lds16(Ag + (size_t)(ktn) * 64 + 65536,  &LA[B][4096 + loA]); \
                         gload_lds16(Ag + (size_t)(ktn) * 64 + 196608, &LA[B][12288 + loA]); }
#define STG_U3(B, ktn) { gload_lds16(Wg + (size_t)(ktn) * 64,          &LB[B][loB]); \
                         gload_lds16(Wg + (size_t)(ktn) * 64 + 131072, &LB[B][8192 + loB]); }
#define STG_U1(B, ktn) { gload_lds16(Wg + (size_t)(ktn) * 64 + 32768,  &LB[B][2048 + loB]); \
                         gload_lds16(Wg + (size_t)(ktn) * 64 + 163840, &LB[B][10240 + loB]); }
#define LDA(B, mh) { _Pragma("unroll") for (int mt = 0; mt < 4; mt++) { \
        const bf16_t* p_ = &LA[B][arow + (mh) * 4096 + mt * 1024]; \
        af[mt][0] = *reinterpret_cast<const bf16x8*>(p_ + ea0); \
        af[mt][1] = *reinterpret_cast<const bf16x8*>(p_ + ea1); } }
#define LDB(B, nh) { _Pragma("unroll") for (int nt = 0; nt < 2; nt++) { \
        const bf16_t* p_ = &LB[B][brow + (nh) * 2048 + nt * 1024]; \
        bfr[nh][nt][0] = *reinterpret_cast<const bf16x8*>(p_ + ea0); \
        bfr[nh][nt][1] = *reinterpret_cast<const bf16x8*>(p_ + ea1); } }
#define MMAQ(mh, nh) { _Pragma("unroll") for (int mt = 0; mt < 4; mt++) \
        _Pragma("unroll") for (int nt = 0; nt < 2; nt++) { \
            acc[(mh)*4+mt][(nh)*2+nt] = MFMA16(af[mt][0], bfr[nh][nt][0], acc[(mh)*4+mt][(nh)*2+nt]); \
            acc[(mh)*4+mt][(nh)*2+nt] = MFMA16(af[mt][1], bfr[nh][nt][1], acc[(mh)*4+mt][(nh)*2+nt]); } }
#define BARX() __builtin_amdgcn_s_barrier()
#define PR1() __builtin_amdgcn_s_setprio(1)
#define PR0() __builtin_amdgcn_s_setprio(0)
#define WAIT_LGKM() { asm volatile("s_waitcnt lgkmcnt(0)" ::: "memory"); \
                      __builtin_amdgcn_sched_barrier(0); }
#define VMC6() { asm volatile("s_waitcnt vmcnt(6)" ::: "memory"); \
                 __builtin_amdgcn_sched_barrier(0); }
#define VMC0() { asm volatile("s_waitcnt vmcnt(0)" ::: "memory"); \
                 __builtin_amdgcn_sched_barrier(0); }
#define VMNONE() {}

    // TILE(B = buffer of tile t, S3 = stage U3(kt1), SN = stage U0/U1/U2(kt2),
    //      RA = read-ahead next tile's A0/B0 after the boundary wait)
#define TILE(B, S3, SN, kt1, kt2, VMW, RA) { \
        /* P0: frags A0,B0 pre-read at previous P3 */ \
        if (S3) STG_U3((B) ^ 1, kt1); \
        BARX(); WAIT_LGKM(); PR1(); MMAQ(0, 0); PR0(); BARX(); \
        /* P1 */ LDB(B, 1); \
        if (SN) STG_U0(B, kt2); \
        BARX(); WAIT_LGKM(); PR1(); MMAQ(0, 1); PR0(); BARX(); \
        /* P2 */ LDA(B, 1); \
        if (SN) STG_U1(B, kt2); \
        BARX(); WAIT_LGKM(); PR1(); MMAQ(1, 0); PR0(); BARX(); \
        /* P3 */ \
        if (SN) STG_U2(B, kt2); \
        BARX(); PR1(); MMAQ(1, 1); PR0(); \
        VMW; \
        if (RA) { LDA((B) ^ 1, 0); LDB((B) ^ 1, 0); } \
        BARX(); }

    // prologue: tile0 complete + tile1 U0,U1,U2; vmcnt(6) completes tile 0;
    // then pre-read tile 0's A0/B0 (waited at tile 0 P0).
    STG_U0(0, 0); STG_U1(0, 0); STG_U2(0, 0); STG_U3(0, 0);
    STG_U0(1, 1); STG_U1(1, 1); STG_U2(1, 1);
    VMC6(); BARX();
    LDA(0, 0); LDB(0, 0);

    for (int t = 0; t < 14; t += 2) {
        TILE(0, 1, 1, t + 1, t + 2, VMC6(), 1);
        TILE(1, 1, 1, t + 2, t + 3, VMC6(), 1);
    }
    TILE(0, 1, 0, 15, 0, VMC0(), 1);   // tile 14: stage U3(15), drain, pre-read 15
    TILE(1, 0, 0, 0, 0, VMNONE(), 0);  // tile 15: no staging, no wait

#undef TILE
#undef STG_U0
#undef STG_U1
#undef STG_U2
#undef STG_U3
#undef LDA
#undef LDB
#undef MMAQ

    if (nb < 2) {
#pragma unroll
        for (int mt = 0; mt < 8; mt++) {
            int mrow = m0 + wm * 128 + mt * 16 + qd * 4;
#pragma unroll
            for (int nt = 0; nt < 4; nt++) {
                int j = n0 + wn * 64 + nt * 16 + L15;
#pragma unroll
                for (int r = 0; r < 4; r++)
                    G[(size_t)(mrow + r) * 512 + j] = (bf16_t)acc[mt][nt][r];
            }
        }
    } else {
#pragma unroll
        for (int mt = 0; mt < 8; mt++) {
            int mrow = m0 + wm * 128 + mt * 16 + qd * 4;
            int n = mrow >> 6, kl = mrow & 63;
#pragma unroll
            for (int nt = 0; nt < 4; nt++) {
                int dloc = (n0 - 512) + wn * 64 + nt * 16 + L15;
                bf16x4 pk;
#pragma unroll
                for (int r = 0; r < 4; r++) pk[r] = (bf16_t)acc[mt][nt][r];
                *reinterpret_cast<bf16x4*>(&VT[(size_t)n * 32768 + (size_t)dloc * 64 + kl]) = pk;
            }
        }
    }
}

// ---------------------------------------------------------------------------
// K3 k_attn: unchanged (1024-block version from the best-measured run).
// ---------------------------------------------------------------------------
__global__ __launch_bounds__(256) void k_attn(
    const bf16_t* __restrict__ A,
    const bf16_t* __restrict__ G, const bf16_t* __restrict__ VT,
    const float* __restrict__ lng, const float* __restrict__ lnb,
    float* __restrict__ out)
{
    __shared__ float  Sl[16][68];
    __shared__ bf16_t Sp[16][72];
    __shared__ float  Rs[4][16];
    __shared__ float  Rq[4][16];
    const int n = blockIdx.x & 255, ks4 = blockIdx.x >> 8;
    const int tid = threadIdx.x, lane = tid & 63, w = tid >> 6;
    const int L15 = lane & 15, qd = lane >> 4;
    const bf16_t* Gb = G + (size_t)n * 32768 + (size_t)(ks4 * 16) * 512;
    const bf16_t* Vb = VT + (size_t)n * 32768;
    const bf16_t* Ab = A + (size_t)n * 64 * 1024;

    bf16x8 bv[2][8];
#pragma unroll
    for (int kq = 0; kq < 2; kq++)
#pragma unroll
        for (int dt = 0; dt < 8; dt++)
            bv[kq][dt] = ldg8(Vb + (size_t)(w * 128 + dt * 16 + L15) * 64 + kq * 32 + qd * 8);

    {   // logits[16 k-rows][q-tile w], two independent MFMA chains
        f32x4 lg0 = (f32x4){0.f, 0.f, 0.f, 0.f};
        f32x4 lg1 = (f32x4){0.f, 0.f, 0.f, 0.f};
        const bf16_t* ga = Gb + (size_t)L15 * 512 + qd * 8;
        const bf16_t* ab = Ab + (size_t)(w * 16 + L15) * 1024 + qd * 8;
#pragma unroll
        for (int ks = 0; ks < 16; ks += 2) {
            lg0 = MFMA16(ldg8(ga + ks * 32),      ldg8(ab + ks * 32),      lg0);
            lg1 = MFMA16(ldg8(ga + ks * 32 + 32), ldg8(ab + ks * 32 + 32), lg1);
        }
        f32x4 lg = lg0 + lg1;
#pragma unroll
        for (int r = 0; r < 4; r++)
            Sl[qd * 4 + r][w * 16 + L15] = lg[r];
    }
    __syncthreads();
    {   // softmax over q (64): 16 threads/row, 4 cols each
        int row = tid >> 4, c0 = (tid & 15) * 4;
        float4 v = *reinterpret_cast<float4*>(&Sl[row][c0]);
        float mx = fmaxf(fmaxf(v.x, v.y), fmaxf(v.z, v.w));
#pragma unroll
        for (int m = 1; m < 16; m <<= 1) mx = fmaxf(mx, __shfl_xor(mx, m));
        float e0 = __expf(v.x - mx), e1 = __expf(v.y - mx);
        float e2 = __expf(v.z - mx), e3 = __expf(v.w - mx);
        float s = e0 + e1 + e2 + e3;
#pragma unroll
        for (int m = 1; m < 16; m <<= 1) s += __shfl_xor(s, m);
        float inv = 1.0f / s;
        bf16x4 p;
        p[0] = (bf16_t)(e0 * inv); p[1] = (bf16_t)(e1 * inv);
        p[2] = (bf16_t)(e2 * inv); p[3] = (bf16_t)(e3 * inv);
        *reinterpret_cast<bf16x4*>(&Sp[row][c0]) = p;
    }
    __syncthreads();

    f32x4 acc[8];
#pragma unroll
    for (int dt = 0; dt < 8; dt++) acc[dt] = (f32x4){0.f, 0.f, 0.f, 0.f};
#pragma unroll
    for (int kq = 0; kq < 2; kq++) {
        bf16x8 ap = *reinterpret_cast<bf16x8*>(&Sp[L15][kq * 32 + qd * 8]);
#pragma unroll
        for (int dt = 0; dt < 8; dt++)
            acc[dt] = MFMA16(ap, bv[kq][dt], acc[dt]);
    }
    float s4[4] = {0.f, 0.f, 0.f, 0.f}, ss4[4] = {0.f, 0.f, 0.f, 0.f};
#pragma unroll
    for (int dt = 0; dt < 8; dt++)
#pragma unroll
        for (int r = 0; r < 4; r++) { float x = acc[dt][r]; s4[r] += x; ss4[r] += x * x; }
#pragma unroll
    for (int m = 1; m < 16; m <<= 1)
#pragma unroll
        for (int r = 0; r < 4; r++) {
            s4[r]  += __shfl_xor(s4[r], m);
            ss4[r] += __shfl_xor(ss4[r], m);
        }
    if (L15 == 0)
#pragma unroll
        for (int r = 0; r < 4; r++) {
            int row = qd * 4 + r;
            Rs[w][row] = s4[r];
            Rq[w][row] = ss4[r];
        }
    __syncthreads();
    float mean[4], rstd[4];
#pragma unroll
    for (int r = 0; r < 4; r++) {
        int row = qd * 4 + r;
        float S = Rs[0][row] + Rs[1][row] + Rs[2][row] + Rs[3][row];
        float Q = Rq[0][row] + Rq[1][row] + Rq[2][row] + Rq[3][row];
        float mu = S * (1.f / 512.f);
        float var = Q * (1.f / 512.f) - mu * mu;
        mean[r] = mu;
        rstd[r] = rsqrtf(var + 1e-5f);
    }
    float* ob = out + (size_t)n * 32768 + (size_t)(ks4 * 16) * 512;
#pragma unroll
    for (int dt = 0; dt < 8; dt++) {
        int col = w * 128 + dt * 16 + L15;
        float gg = lng[col], bb = lnb[col];
#pragma unroll
        for (int r = 0; r < 4; r++) {
            int row = qd * 4 + r;
            ob[(size_t)row * 512 + col] = (acc[dt][r] - mean[r]) * rstd[r] * gg + bb;
        }
    }
}

// ---------------------------------------------------------------------------
// Fallback fused per-batch kernel — only if ws too small.
// ---------------------------------------------------------------------------
__global__ __launch_bounds__(1024) void k_batch_fb(
    const float* __restrict__ H, const float* __restrict__ Z,
    const bf16_t* __restrict__ W,
    const float* __restrict__ lng, const float* __restrict__ lnb,
    float* __restrict__ out)
{
    __shared__ __align__(16) char lds_raw[48128];
    bf16_t* lds_bf = (bf16_t*)lds_raw;
    float*  lds_f  = (float*)lds_raw;
    bf16_t* Gbuf = lds_bf;
    float*  Sl   = lds_f;
    bf16_t* VTl  = lds_bf;
    bf16_t* Sp   = lds_bf + 18432;
    float*  Rs   = lds_f + 11520;
    float*  Rq   = lds_f + 11776;

    const int n = blockIdx.x;
    const int tid = threadIdx.x, lane = tid & 63, w = tid >> 6;
    const int L15 = lane & 15, qd = lane >> 4;
    const int strip = w & 3, grp = w >> 2;
    const float* Hb = H + (size_t)n * 32768;
    const float* Zb = Z + (size_t)n * 32768;

    f32x4 a1 = (f32x4){0.f, 0.f, 0.f, 0.f};
    for (int hf = 0; hf < 2; hf++) {
        f32x4 ga[4];
#pragma unroll
        for (int mt = 0; mt < 4; mt++) ga[mt] = (f32x4){0.f, 0.f, 0.f, 0.f};
        const bf16_t* wrow = W + (size_t)(hf * 256 + w * 16 + L15) * 1024;
#pragma unroll 4
        for (int kc = 0; kc < 16; kc++) {
            const int ko = kc * 32 + qd * 8;
            bf16x8 bh = ldg8(wrow + ko);
            bf16x8 bz = ldg8(wrow + 512 + ko);
#pragma unroll
            for (int mt = 0; mt < 4; mt++) {
                bf16x8 ah = ld8f(Hb + (size_t)(mt * 16 + L15) * 512 + ko);
                bf16x8 az = ld8f(Zb + (size_t)(mt * 16 + L15) * 512 + ko);
                ga[mt] = MFMA16(ah, bh, ga[mt]);
                ga[mt] = MFMA16(az, bz, ga[mt]);
            }
        }
        __syncthreads();
#pragma unroll
        for (int mt = 0; mt < 4; mt++)
#pragma unroll
            for (int r = 0; r < 4; r++)
                Gbuf[(size_t)(mt * 16 + qd * 4 + r) * 264 + w * 16 + L15] = (bf16_t)ga[mt][r];
        __syncthreads();
#pragma unroll
        for (int kcf = 0; kcf < 8; kcf++) {
            bf16x8 af = *reinterpret_cast<bf16x8*>(
                &Gbuf[(size_t)(strip * 16 + L15) * 264 + kcf * 32 + qd * 8]);
            bf16x8 bq = ld8f(Hb + (size_t)(grp * 16 + L15) * 512 + hf * 256 + kcf * 32 + qd * 8);
            a1 = MFMA16(af, bq, a1);
        }
    }
    __syncthreads();
#pragma unroll
    for (int r = 0; r < 4; r++)
        Sl[(size_t)(strip * 16 + qd * 4 + r) * 64 + grp * 16 + L15] = a1[r];
    __syncthreads();
    {
        int row = tid >> 4, c0 = (tid & 15) * 4;
        float4 v = *reinterpret_cast<float4*>(&Sl[(size_t)row * 64 + c0]);
        float mx = fmaxf(fmaxf(v.x, v.y), fmaxf(v.z, v.w));
#pragma unroll
        for (int m = 1; m < 16; m <<= 1) mx = fmaxf(mx, __shfl_xor(mx, m));
        float e0 = __expf(v.x - mx), e1 = __expf(v.y - mx);
        float e2 = __expf(v.z - mx), e3 = __expf(v.w - mx);
        float s = e0 + e1 + e2 + e3;
#pragma unroll
        for (int m = 1; m < 16; m <<= 1) s += __shfl_xor(s, m);
        float inv = 1.0f / s;
        bf16x4 p;
        p[0] = (bf16_t)(e0 * inv); p[1] = (bf16_t)(e1 * inv);
        p[2] = (bf16_t)(e2 * inv); p[3] = (bf16_t)(e3 * inv);
        *reinterpret_cast<bf16x4*>(&Sp[(size_t)row * 72 + c0]) = p;
    }
    __syncthreads();

    f32x4 acc[8];
#pragma unroll
    for (int j = 0; j < 8; j++) acc[j] = (f32x4){0.f, 0.f, 0.f, 0.f};
    for (int hf2 = 0; hf2 < 2; hf2++) {
        f32x4 va[4];
#pragma unroll
        for (int mt = 0; mt < 4; mt++) va[mt] = (f32x4){0.f, 0.f, 0.f, 0.f};
        const bf16_t* wrow = W + (size_t)(512 + hf2 * 256 + w * 16 + L15) * 1024;
#pragma unroll 4
        for (int kc = 0; kc < 16; kc++) {
            const int ko = kc * 32 + qd * 8;
            bf16x8 bh = ldg8(wrow + ko);
            bf16x8 bz = ldg8(wrow + 512 + ko);
#pragma unroll
            for (int mt = 0; mt < 4; mt++) {
                bf16x8 ah = ld8f(Hb + (size_t)(mt * 16 + L15) * 512 + ko);
                bf16x8 az = ld8f(Zb + (size_t)(mt * 16 + L15) * 512 + ko);
                va[mt] = MFMA16(ah, bh, va[mt]);
                va[mt] = MFMA16(az, bz, va[mt]);
            }
        }
#pragma unroll
        for (int mt = 0; mt < 4; mt++) {
            bf16x4 pk;
#pragma unroll
            for (int r = 0; r < 4; r++) pk[r] = (bf16_t)va[mt][r];
            *reinterpret_cast<bf16x4*>(&VTl[(size_t)(w * 16 + L15) * 72 + mt * 16 + qd * 4]) = pk;
        }
        __syncthreads();
#pragma unroll
        for (int kcq = 0; kcq < 2; kcq++) {
            bf16x8 ap = *reinterpret_cast<bf16x8*>(
                &Sp[(size_t)(strip * 16 + L15) * 72 + kcq * 32 + qd * 8]);
#pragma unroll
            for (int dt = 0; dt < 4; dt++) {
                bf16x8 bvl = *reinterpret_cast<bf16x8*>(
                    &VTl[(size_t)(grp * 64 + dt * 16 + L15) * 72 + kcq * 32 + qd * 8]);
                acc[hf2 * 4 + dt] = MFMA16(ap, bvl, acc[hf2 * 4 + dt]);
            }
        }
        __syncthreads();
    }
    float s4[4] = {0.f, 0.f, 0.f, 0.f}, ss4[4] = {0.f, 0.f, 0.f, 0.f};
#pragma unroll
    for (int j = 0; j < 8; j++)
#pragma unroll
        for (int r = 0; r < 4; r++) { float x = acc[j][r]; s4[r] += x; ss4[r] += x * x; }
#pragma unroll
    for (int m = 1; m < 16; m <<= 1)
#pragma unroll
        for (int r = 0; r < 4; r++) {
            s4[r]  += __shfl_xor(s4[r], m);
            ss4[r] += __shfl_xor(ss4[r], m);
        }
    if (L15 == 0)
#pragma unroll
        for (int r = 0; r < 4; r++) {
            int row = strip * 16 + qd * 4 + r;
            Rs[grp * 64 + row] = s4[r];
            Rq[grp * 64 + row] = ss4[r];
        }
    __syncthreads();
    float mean[4], rstd[4];
#pragma unroll
    for (int r = 0; r < 4; r++) {
        int row = strip * 16 + qd * 4 + r;
        float S = Rs[row] + Rs[64 + row] + Rs[128 + row] + Rs[192 + row];
        float Q = Rq[row] + Rq[64 + row] + Rq[128 + row] + Rq[192 + row];
        float mu = S * (1.f / 512.f);
        float var = Q * (1.f / 512.f) - mu * mu;
        mean[r] = mu;
        rstd[r] = rsqrtf(var + 1e-5f);
    }
#pragma unroll
    for (int j = 0; j < 8; j++) {
        int col = (j >> 2) * 256 + grp * 64 + (j & 3) * 16 + L15;
        float gg = lng[col], bb = lnb[col];
#pragma unroll
        for (int r = 0; r < 4; r++) {
            int row = strip * 16 + qd * 4 + r;
            out[(size_t)n * 32768 + (size_t)row * 512 + col] =
                (acc[j][r] - mean[r]) * rstd[r] * gg + bb;
        }
    }
}

extern "C" void kernel_launch(void* const* d_in, const int* in_sizes, int n_in,
                              void* d_out, int out_size, void* d_ws, size_t ws_size,
                              hipStream_t stream) {
    const float* H    = (const float*)d_in[0];
    const float* Z    = (const float*)d_in[1];
    const float* Whk  = (const float*)d_in[2];
    const float* Whv  = (const float*)d_in[3];
    const float* Wzk  = (const float*)d_in[4];
    const float* Wzv  = (const float*)d_in[5];
    const float* Wq   = (const float*)d_in[6];
    const float* Wout = (const float*)d_in[7];
    const float* lng  = (const float*)d_in[8];
    const float* lnb  = (const float*)d_in[9];

    bf16_t* W  = (bf16_t*)d_ws;            // [1024][1024]    2 MiB
    bf16_t* A  = W + 1024 * 1024;          // [16384][1024]  32 MiB
    bf16_t* G  = A + (size_t)16384 * 1024; // [16384][512]   16 MiB
    bf16_t* VT = G + (size_t)16384 * 512;  // [256][512][64] 16 MiB
    const size_t need = ((size_t)1024 * 1024 + (size_t)16384 * 1024 +
                         (size_t)16384 * 512 + (size_t)256 * 512 * 64) * 2;

    if (ws_size >= need) {
        k_prep<<<8448, 256, 0, stream>>>(H, Z, Whk, Whv, Wzk, Wzv, Wq, Wout, W, A);
        k_gemm<<<256, 512, 0, stream>>>(A, W, G, VT);
        k_attn<<<1024, 256, 0, stream>>>(A, G, VT, lng, lnb, (float*)d_out);
    } else {
        k_prep<<<256, 256, 0, stream>>>(H, Z, Whk, Whv, Wzk, Wzv, Wq, Wout, W, A);
        k_batch_fb<<<256, 1024, 0, stream>>>(H, Z, W, lng, lnb, (float*)d_out);
    }
}